// Round 1
// baseline (7501.836 us; speedup 1.0000x reference)
//
#include <hip/hip_runtime.h>
#include <math.h>

#define SDIM 2048
#define BATCH 1024
#define NITER 16
#define LM 160   // Lanczos steps

__device__ __forceinline__ float softt(float v, float th){
  return copysignf(fmaxf(fabsf(v) - th, 0.0f), v);
}

// ---------------- Lanczos kernels: L = lambda_max(W^T W) ----------------

__global__ __launch_bounds__(256) void k_init(float* __restrict__ v, float* __restrict__ vprev,
                                              float* __restrict__ betaArr){
  __shared__ float red[256];
  int t = threadIdx.x;
  float vals[8];
  float s = 0.f;
  #pragma unroll
  for (int p = 0; p < 8; p++){
    int j = p*256 + t;
    unsigned h = (unsigned)j * 2654435761u;
    h ^= h >> 16; h *= 2246822519u; h ^= h >> 13;
    float r = (float)(h & 0xFFFFFFu) / 16777216.0f - 0.5f;
    vals[p] = r; s += r*r;
  }
  red[t] = s; __syncthreads();
  for (int o = 128; o > 0; o >>= 1){ if (t < o) red[t] += red[t+o]; __syncthreads(); }
  float inv = rsqrtf(red[0]);
  #pragma unroll
  for (int p = 0; p < 8; p++){ int j = p*256 + t; v[j] = vals[p]*inv; vprev[j] = 0.f; }
  if (t == 0) betaArr[0] = 0.f;
}

// u = W v   (512 blocks x 256, one row per wave)
__global__ __launch_bounds__(256) void k_mv1(const float* __restrict__ W, const float* __restrict__ v,
                                             float* __restrict__ u){
  int wave = threadIdx.x >> 6, lane = threadIdx.x & 63;
  int row = blockIdx.x*4 + wave;
  const float4* Wr = (const float4*)(W + (size_t)row * SDIM);
  const float4* v4 = (const float4*)v;
  float s = 0.f;
  #pragma unroll
  for (int p = 0; p < 8; p++){
    int j4 = p*64 + lane;
    float4 a = Wr[j4], b = v4[j4];
    s += a.x*b.x + a.y*b.y + a.z*b.z + a.w*b.w;
  }
  #pragma unroll
  for (int o = 32; o > 0; o >>= 1) s += __shfl_down(s, o);
  if (lane == 0) u[row] = s;
}

// wpart[ic][j] = sum over i-chunk of W[i][j]*u[i]   grid (8 jb, 8 ic)
__global__ __launch_bounds__(256) void k_mv2(const float* __restrict__ W, const float* __restrict__ u,
                                             float* __restrict__ wpart){
  __shared__ float us[256];
  int jb = blockIdx.x, ic = blockIdx.y;
  int j = jb*256 + threadIdx.x;
  us[threadIdx.x] = u[ic*256 + threadIdx.x];
  __syncthreads();
  float acc = 0.f;
  const float* Wp = W + (size_t)(ic*256) * SDIM + j;
  #pragma unroll 8
  for (int i = 0; i < 256; i++) acc = fmaf(Wp[(size_t)i*SDIM], us[i], acc);
  wpart[ic*SDIM + j] = acc;
}

// finish step: w = sum partials; alpha; w' = w - a v - b vprev; beta; vnext
__global__ __launch_bounds__(256) void k_mv3(const float* __restrict__ wpart, const float* __restrict__ vcur,
                                             const float* __restrict__ vprev, float* __restrict__ vnext,
                                             float* __restrict__ alphaArr, float* __restrict__ betaArr, int step){
  __shared__ float wbuf[SDIM];
  __shared__ float red[256];
  int t = threadIdx.x;
  float dp = 0.f;
  #pragma unroll
  for (int p = 0; p < 8; p++){
    int j = p*256 + t;
    float w = 0.f;
    #pragma unroll
    for (int ic = 0; ic < 8; ic++) w += wpart[ic*SDIM + j];
    wbuf[j] = w;
    dp += w * vcur[j];
  }
  red[t] = dp; __syncthreads();
  for (int o = 128; o > 0; o >>= 1){ if (t < o) red[t] += red[t+o]; __syncthreads(); }
  float alpha = red[0];
  float bprev = betaArr[step-1];
  __syncthreads();
  float wp[8];
  float nrm = 0.f;
  #pragma unroll
  for (int p = 0; p < 8; p++){
    int j = p*256 + t;
    float w2 = wbuf[j] - alpha*vcur[j] - bprev*vprev[j];
    wp[p] = w2; nrm += w2*w2;
  }
  red[t] = nrm; __syncthreads();
  for (int o = 128; o > 0; o >>= 1){ if (t < o) red[t] += red[t+o]; __syncthreads(); }
  float beta = sqrtf(red[0]);
  float invb = 1.0f / fmaxf(beta, 1e-30f);
  #pragma unroll
  for (int p = 0; p < 8; p++){ int j = p*256 + t; vnext[j] = wp[p]*invb; }
  if (t == 0){ alphaArr[step] = alpha; betaArr[step] = beta; }
}

// lambda_max of tridiagonal via lane-parallel Sturm bisection (fp64), 1 wave
__global__ void k_sturm(const float* __restrict__ alphaArr, const float* __restrict__ betaArr,
                        const float* __restrict__ alphaIn, float* __restrict__ Lbuf){
  __shared__ double sa[LM+1], sb[LM+1];
  int lane = threadIdx.x;
  for (int i = lane; i <= LM; i += 64){ if (i >= 1){ sa[i] = alphaArr[i]; sb[i] = betaArr[i]; } }
  __syncthreads();
  double phi = -1e300, plo = 1e300;
  for (int i = 1 + lane; i <= LM; i += 64){
    double r = (i > 1 ? sb[i-1] : 0.0) + (i < LM ? sb[i] : 0.0);
    phi = fmax(phi, sa[i] + r);
    plo = fmin(plo, sa[i] - r);
  }
  for (int o = 32; o > 0; o >>= 1){
    phi = fmax(phi, __shfl_down(phi, o));
    plo = fmin(plo, __shfl_down(plo, o));
  }
  double hi = __shfl(phi, 0), lo = __shfl(plo, 0);
  for (int round = 0; round < 6; round++){
    double x = lo + (hi - lo) * (double)(lane + 1) / 65.0;
    int cnt = 0;
    double dd = sa[1] - x;
    if (dd < 0) cnt++;
    for (int i = 2; i <= LM; i++){
      double off = sb[i-1];
      if (fabs(dd) < 1e-300) dd = -1e-300;
      dd = sa[i] - x - off*off/dd;
      if (dd < 0) cnt++;
    }
    unsigned long long bal = __ballot(cnt == LM);
    int p = (bal == 0ull) ? 64 : (__ffsll((unsigned long long)bal) - 1);
    double newhi = (p <= 63) ? lo + (hi - lo) * (double)(p + 1) / 65.0 : hi;
    double newlo = (p >= 1)  ? lo + (hi - lo) * (double)p / 65.0       : lo;
    hi = newhi; lo = newlo;
  }
  if (lane == 0){
    double L = 0.5*(lo + hi);
    Lbuf[0] = (float)(1.0 / L);
    Lbuf[1] = (float)(0.5 * (double)alphaIn[0] / L);
  }
}

// ---------------- FISTA kernels ----------------

// iteration 0 elementwise part (y0 = 0): res = Y, sres = src*Y, delta-half update
__global__ __launch_bounds__(256) void k_A0(const float* __restrict__ Y, const float* __restrict__ src,
                                            float* __restrict__ yd, float* __restrict__ sres,
                                            float* __restrict__ out, const float* __restrict__ Lbuf){
  int idx = blockIdx.x*256 + threadIdx.x;
  float invL = Lbuf[0], th = Lbuf[1];
  float y = Y[idx], s = src[idx];
  sres[idx] = s*y;
  float vd = y*invL;
  float xn = softt(vd, th);
  int b = idx >> 11, i = idx & 2047;
  out[(size_t)b*4096 + 2048 + i] = xn;
  yd[idx] = xn;   // c0 = 0 -> y1 = x1
}

// GEMM1: C[b][i] = sum_k ym[b][k]*W[i][k]; fused: res, sres, delta(x,y) update
__global__ __launch_bounds__(256) void k_gemmA(
    const float* __restrict__ W, const float* __restrict__ ym,
    const float* __restrict__ Y, const float* __restrict__ src,
    float* __restrict__ yd, float* __restrict__ out, float* __restrict__ sres,
    const float* __restrict__ Lbuf, float ck)
{
  constexpr int LDA = 76;
  __shared__ __align__(16) float As[16*LDA];
  __shared__ __align__(16) float Bs[16*LDA];
  const int tid = threadIdx.x;
  const int tx = tid & 15, ty = tid >> 4;
  const int m0 = blockIdx.y * 64, n0 = blockIdx.x * 64;
  const int lr = tid >> 2;
  const int lc = (tid & 3) << 2;
  const float* Ag = ym + (size_t)(m0 + lr) * SDIM + lc;
  const float* Bg = W  + (size_t)(n0 + lr) * SDIM + lc;
  float acc[4][4] = {};
  for (int kt = 0; kt < SDIM/16; kt++){
    float4 av = *(const float4*)Ag;
    float4 bv = *(const float4*)Bg;
    Ag += 16; Bg += 16;
    __syncthreads();
    As[(lc+0)*LDA + lr] = av.x;
    As[(lc+1)*LDA + lr] = av.y;
    As[(lc+2)*LDA + lr] = av.z;
    As[(lc+3)*LDA + lr] = av.w;
    Bs[(lc+0)*LDA + lr] = bv.x;
    Bs[(lc+1)*LDA + lr] = bv.y;
    Bs[(lc+2)*LDA + lr] = bv.z;
    Bs[(lc+3)*LDA + lr] = bv.w;
    __syncthreads();
    #pragma unroll
    for (int kk = 0; kk < 16; kk++){
      const float4 a = *(const float4*)&As[kk*LDA + ty*4];
      const float4 b = *(const float4*)&Bs[kk*LDA + tx*4];
      float af[4] = {a.x, a.y, a.z, a.w};
      float bf[4] = {b.x, b.y, b.z, b.w};
      #pragma unroll
      for (int r = 0; r < 4; r++)
        #pragma unroll
        for (int c = 0; c < 4; c++)
          acc[r][c] = fmaf(af[r], bf[c], acc[r][c]);
    }
  }
  const float invL = Lbuf[0], th = Lbuf[1];
  #pragma unroll
  for (int r = 0; r < 4; r++){
    const int b = m0 + ty*4 + r;
    #pragma unroll
    for (int c = 0; c < 4; c++){
      const int i = n0 + tx*4 + c;
      const size_t g = (size_t)b*SDIM + i;
      const float s = src[g];
      const float ydv = yd[g];
      const float res = Y[g] - s*acc[r][c] - ydv;
      sres[g] = s*res;
      const float vd = ydv + res*invL;
      const float xn = softt(vd, th);
      const float xo = out[(size_t)b*4096 + 2048 + i];
      const float yn = xn + ck*(xn - xo);
      out[(size_t)b*4096 + 2048 + i] = xn;
      yd[g] = yn;
    }
  }
}

// GEMM2: C[b][j] = sum_i sres[b][i]*W[i][j]; fused: theta(x,y) update
template<bool FIRST>
__global__ __launch_bounds__(256) void k_gemmB(
    const float* __restrict__ W, const float* __restrict__ sres,
    float* __restrict__ ym, float* __restrict__ out,
    const float* __restrict__ Lbuf, float ck)
{
  constexpr int LDA = 76;
  constexpr int LDB = 68;
  __shared__ __align__(16) float As[16*LDA];
  __shared__ __align__(16) float Bs[16*LDB];
  const int tid = threadIdx.x;
  const int tx = tid & 15, ty = tid >> 4;
  const int m0 = blockIdx.y * 64, n0 = blockIdx.x * 64;
  const int lr = tid >> 2;
  const int lc = (tid & 3) << 2;
  const int bk = tid >> 4;
  const int bn = (tid & 15) << 2;
  const float* Ag = sres + (size_t)(m0 + lr) * SDIM + lc;
  const float* Bg = W + (size_t)bk * SDIM + n0 + bn;
  float acc[4][4] = {};
  for (int kt = 0; kt < SDIM/16; kt++){
    float4 av = *(const float4*)Ag;
    float4 bv = *(const float4*)Bg;
    Ag += 16; Bg += (size_t)16 * SDIM;
    __syncthreads();
    As[(lc+0)*LDA + lr] = av.x;
    As[(lc+1)*LDA + lr] = av.y;
    As[(lc+2)*LDA + lr] = av.z;
    As[(lc+3)*LDA + lr] = av.w;
    *(float4*)&Bs[bk*LDB + bn] = bv;
    __syncthreads();
    #pragma unroll
    for (int kk = 0; kk < 16; kk++){
      const float4 a = *(const float4*)&As[kk*LDA + ty*4];
      const float4 b = *(const float4*)&Bs[kk*LDB + tx*4];
      float af[4] = {a.x, a.y, a.z, a.w};
      float bf[4] = {b.x, b.y, b.z, b.w};
      #pragma unroll
      for (int r = 0; r < 4; r++)
        #pragma unroll
        for (int c = 0; c < 4; c++)
          acc[r][c] = fmaf(af[r], bf[c], acc[r][c]);
    }
  }
  const float invL = Lbuf[0], th = Lbuf[1];
  #pragma unroll
  for (int r = 0; r < 4; r++){
    const int b = m0 + ty*4 + r;
    #pragma unroll
    for (int c = 0; c < 4; c++){
      const int j = n0 + tx*4 + c;
      const size_t g = (size_t)b*SDIM + j;
      const float vm = (FIRST ? 0.0f : ym[g]) + acc[r][c]*invL;
      const float xn = softt(vm, th);
      const float xo = FIRST ? 0.0f : out[(size_t)b*4096 + j];
      const float yn = xn + ck*(xn - xo);
      out[(size_t)b*4096 + j] = xn;
      ym[g] = yn;
    }
  }
}

// ---------------- host ----------------

extern "C" void kernel_launch(void* const* d_in, const int* in_sizes, int n_in,
                              void* d_out, int out_size, void* d_ws, size_t ws_size,
                              hipStream_t stream) {
  const float* src   = (const float*)d_in[0];
  const float* Y     = (const float*)d_in[1];
  const float* W     = (const float*)d_in[2];
  const float* alpha = (const float*)d_in[3];
  float* out = (float*)d_out;
  float* ws  = (float*)d_ws;

  const size_t NM = (size_t)BATCH * SDIM;
  float* ym   = ws;
  float* yd   = ws + NM;
  float* sres = ws + 2*NM;
  float* vb      = ws + 3*NM;
  float* u       = vb + 3*SDIM;
  float* wpart   = u + SDIM;
  float* alphaArr= wpart + 8*SDIM;
  float* betaArr = alphaArr + 256;
  float* Lbuf    = betaArr + 256;

  // ---- Lanczos for L = lambda_max(W^T W) ----
  float* v[3] = { vb, vb + SDIM, vb + 2*SDIM };
  k_init<<<1, 256, 0, stream>>>(v[0], v[2], betaArr);
  int cur = 0, prev = 2, nxt = 1;
  for (int step = 1; step <= LM; step++){
    k_mv1<<<512, 256, 0, stream>>>(W, v[cur], u);
    k_mv2<<<dim3(8,8), 256, 0, stream>>>(W, u, wpart);
    k_mv3<<<1, 256, 0, stream>>>(wpart, v[cur], v[prev], v[nxt], alphaArr, betaArr, step);
    prev = cur; cur = nxt; nxt = 3 - cur - prev;
  }
  k_sturm<<<1, 64, 0, stream>>>(alphaArr, betaArr, alpha, Lbuf);

  // ---- momentum coefficients (data independent) ----
  double t = 1.0;
  float ckv[NITER];
  for (int k = 0; k < NITER; k++){
    double tn = 0.5*(1.0 + sqrt(1.0 + 4.0*t*t));
    ckv[k] = (float)((t - 1.0)/tn);
    t = tn;
  }

  // ---- FISTA ----
  k_A0<<<(BATCH*SDIM)/256, 256, 0, stream>>>(Y, src, yd, sres, out, Lbuf);
  k_gemmB<true><<<dim3(32,16), 256, 0, stream>>>(W, sres, ym, out, Lbuf, ckv[0]);
  for (int k = 1; k < NITER; k++){
    k_gemmA<<<dim3(32,16), 256, 0, stream>>>(W, ym, Y, src, yd, out, sres, Lbuf, ckv[k]);
    k_gemmB<false><<<dim3(32,16), 256, 0, stream>>>(W, sres, ym, out, Lbuf, ckv[k]);
  }
  (void)in_sizes; (void)n_in; (void)out_size; (void)ws_size;
}

// Round 2
// 2807.676 us; speedup vs baseline: 2.6719x; 2.6719x over previous
//
#include <hip/hip_runtime.h>
#include <math.h>

#define SDIM 2048
#define BATCH 1024
#define NITER 16
#define LM 96   // Lanczos steps

typedef unsigned short ushort_t;
typedef __attribute__((ext_vector_type(8))) short bf16x8;
typedef __attribute__((ext_vector_type(4))) float f32x4;

#define MFMA(a,b,c) __builtin_amdgcn_mfma_f32_16x16x32_bf16((a),(b),(c),0,0,0)

__device__ __forceinline__ float softt(float v, float th){
  return copysignf(fmaxf(fabsf(v) - th, 0.0f), v);
}

__device__ __forceinline__ float bf2f(ushort_t h){
  return __uint_as_float(((unsigned)h) << 16);
}

// RTNE float -> bf16 hi + bf16 lo split
__device__ __forceinline__ void split2(float x, ushort_t* h, ushort_t* l){
  unsigned u = __float_as_uint(x);
  unsigned hh = (u + 0x7FFFu + ((u >> 16) & 1u)) >> 16;
  float hf = __uint_as_float(hh << 16);
  float r = x - hf;                       // exact
  unsigned v = __float_as_uint(r);
  unsigned ll = (v + 0x7FFFu + ((v >> 16) & 1u)) >> 16;
  *h = (ushort_t)hh; *l = (ushort_t)ll;
}

// async 16B global -> LDS
__device__ __forceinline__ void cp16(const ushort_t* g, ushort_t* l){
  __builtin_amdgcn_global_load_lds(
      (const __attribute__((address_space(1))) unsigned int*)g,
      (__attribute__((address_space(3))) unsigned int*)l, 16, 0, 0);
}

// ---------------- shared MFMA GEMM core ----------------
// C[m][n] = sum_k A[m][k]*B[n][k], A: (M x K) row-major bf16 hi/lo, B: (N x K) row-major.
// 64x64 tile, BK=32, 256 threads = 4 waves of 32x32. acc[2][2] f32x4 per thread.
__device__ __forceinline__ void gemm_core(const ushort_t* __restrict__ Ah, const ushort_t* __restrict__ Al,
                                          const ushort_t* __restrict__ Bh, const ushort_t* __restrict__ Bl,
                                          int m0, int n0, int K, f32x4 acc[2][2])
{
  __shared__ ushort_t lAh[64*32], lAl[64*32], lBh[64*32], lBl[64*32];
  const int tid = threadIdx.x;
  // staging: chunk tid -> LDS offset tid*16B; content row rr, k-part pp (XOR swizzle)
  const int rr = tid >> 2;
  const int pp = (tid & 3) ^ ((rr >> 1) & 3);
  const ushort_t* gAh = Ah + (size_t)(m0 + rr) * K + pp * 8;
  const ushort_t* gAl = Al + (size_t)(m0 + rr) * K + pp * 8;
  const ushort_t* gBh = Bh + (size_t)(n0 + rr) * K + pp * 8;
  const ushort_t* gBl = Bl + (size_t)(n0 + rr) * K + pp * 8;
  ushort_t* dAh = &lAh[tid * 8];
  ushort_t* dAl = &lAl[tid * 8];
  ushort_t* dBh = &lBh[tid * 8];
  ushort_t* dBl = &lBl[tid * 8];

  const int lane = tid & 63, wv = tid >> 6;
  const int wm = (wv >> 1) * 32, wn = (wv & 1) * 32;
  const int mm = lane & 15, quad = lane >> 4;
  const int ra0 = wm + mm,      ra1 = wm + 16 + mm;
  const int rb0 = wn + mm,      rb1 = wn + 16 + mm;
  const int oa0 = ra0*32 + ((quad ^ ((ra0>>1)&3)) << 3);
  const int oa1 = ra1*32 + ((quad ^ ((ra1>>1)&3)) << 3);
  const int ob0 = rb0*32 + ((quad ^ ((rb0>>1)&3)) << 3);
  const int ob1 = rb1*32 + ((quad ^ ((rb1>>1)&3)) << 3);

  const int nk = K / 32;
  for (int kt = 0; kt < nk; kt++){
    cp16(gAh, dAh); cp16(gAl, dAl); cp16(gBh, dBh); cp16(gBl, dBl);
    gAh += 32; gAl += 32; gBh += 32; gBl += 32;
    __syncthreads();   // drains vmcnt -> staged tile visible
    bf16x8 ah0 = *(const bf16x8*)&lAh[oa0];
    bf16x8 ah1 = *(const bf16x8*)&lAh[oa1];
    bf16x8 al0 = *(const bf16x8*)&lAl[oa0];
    bf16x8 al1 = *(const bf16x8*)&lAl[oa1];
    bf16x8 bh0 = *(const bf16x8*)&lBh[ob0];
    bf16x8 bh1 = *(const bf16x8*)&lBh[ob1];
    bf16x8 bl0 = *(const bf16x8*)&lBl[ob0];
    bf16x8 bl1 = *(const bf16x8*)&lBl[ob1];
    acc[0][0] = MFMA(ah0, bh0, acc[0][0]);
    acc[0][0] = MFMA(ah0, bl0, acc[0][0]);
    acc[0][0] = MFMA(al0, bh0, acc[0][0]);
    acc[0][1] = MFMA(ah0, bh1, acc[0][1]);
    acc[0][1] = MFMA(ah0, bl1, acc[0][1]);
    acc[0][1] = MFMA(al0, bh1, acc[0][1]);
    acc[1][0] = MFMA(ah1, bh0, acc[1][0]);
    acc[1][0] = MFMA(ah1, bl0, acc[1][0]);
    acc[1][0] = MFMA(al1, bh0, acc[1][0]);
    acc[1][1] = MFMA(ah1, bh1, acc[1][1]);
    acc[1][1] = MFMA(ah1, bl1, acc[1][1]);
    acc[1][1] = MFMA(al1, bh1, acc[1][1]);
    __syncthreads();   // protect LDS before next stage
  }
}

// ---------------- W split / transpose-split ----------------
__global__ __launch_bounds__(256) void k_split(const float* __restrict__ W,
                                               ushort_t* __restrict__ Wah, ushort_t* __restrict__ Wal,
                                               ushort_t* __restrict__ Wbh, ushort_t* __restrict__ Wbl){
  __shared__ float t[32][33];
  const int i0 = blockIdx.y * 32, j0 = blockIdx.x * 32;
  const int r = threadIdx.x >> 3, c = (threadIdx.x & 7) * 4;
  const float4 v = *(const float4*)&W[(size_t)(i0 + r) * SDIM + j0 + c];
  float vv[4] = {v.x, v.y, v.z, v.w};
  ushort_t h[4], l[4];
  #pragma unroll
  for (int q = 0; q < 4; q++){ split2(vv[q], &h[q], &l[q]); t[r][c+q] = vv[q]; }
  *(ushort4*)&Wah[(size_t)(i0 + r) * SDIM + j0 + c] = make_ushort4(h[0],h[1],h[2],h[3]);
  *(ushort4*)&Wal[(size_t)(i0 + r) * SDIM + j0 + c] = make_ushort4(l[0],l[1],l[2],l[3]);
  __syncthreads();
  #pragma unroll
  for (int q = 0; q < 4; q++) split2(t[c+q][r], &h[q], &l[q]);
  *(ushort4*)&Wbh[(size_t)(j0 + r) * SDIM + i0 + c] = make_ushort4(h[0],h[1],h[2],h[3]);
  *(ushort4*)&Wbl[(size_t)(j0 + r) * SDIM + i0 + c] = make_ushort4(l[0],l[1],l[2],l[3]);
}

// M = W * W^T (same nonzero spectrum as W^T W)
__global__ __launch_bounds__(256) void k_gemmM(const ushort_t* __restrict__ Wah, const ushort_t* __restrict__ Wal,
                                               float* __restrict__ Mmat){
  f32x4 acc[2][2] = {};
  const int m0 = blockIdx.y * 64, n0 = blockIdx.x * 64;
  gemm_core(Wah, Wal, Wah, Wal, m0, n0, SDIM, acc);
  const int tid = threadIdx.x, lane = tid & 63, wv = tid >> 6;
  const int wm = (wv >> 1) * 32, wn = (wv & 1) * 32;
  const int mm = lane & 15, quad = lane >> 4;
  #pragma unroll
  for (int tm = 0; tm < 2; tm++)
    #pragma unroll
    for (int tn = 0; tn < 2; tn++)
      #pragma unroll
      for (int i = 0; i < 4; i++){
        int row = m0 + wm + tm*16 + quad*4 + i;
        int col = n0 + wn + tn*16 + mm;
        Mmat[(size_t)row * SDIM + col] = acc[tm][tn][i];
      }
}

// ---------------- Lanczos on M ----------------
__global__ __launch_bounds__(256) void k_init(float* __restrict__ v, float* __restrict__ vprev,
                                              float* __restrict__ alphaArr, float* __restrict__ betaArr){
  __shared__ float red[256];
  int t = threadIdx.x;
  float vals[8];
  float s = 0.f;
  #pragma unroll
  for (int p = 0; p < 8; p++){
    int j = p*256 + t;
    unsigned h = (unsigned)j * 2654435761u;
    h ^= h >> 16; h *= 2246822519u; h ^= h >> 13;
    float r = (float)(h & 0xFFFFFFu) / 16777216.0f - 0.5f;
    vals[p] = r; s += r*r;
  }
  red[t] = s; __syncthreads();
  for (int o = 128; o > 0; o >>= 1){ if (t < o) red[t] += red[t+o]; __syncthreads(); }
  float inv = rsqrtf(red[0]);
  #pragma unroll
  for (int p = 0; p < 8; p++){ int j = p*256 + t; v[j] = vals[p]*inv; vprev[j] = 0.f; }
  if (t < 128){ alphaArr[t] = 0.f; betaArr[t] = 0.f; }
}

// w = M v, partial alpha = v.w accumulated by atomics
__global__ __launch_bounds__(256) void k_Mv(const float* __restrict__ M, const float* __restrict__ v,
                                            float* __restrict__ w, float* __restrict__ alphaArr, int step){
  int wave = threadIdx.x >> 6, lane = threadIdx.x & 63;
  int row = blockIdx.x*4 + wave;
  const float4* Mr = (const float4*)(M + (size_t)row * SDIM);
  const float4* v4 = (const float4*)v;
  float s = 0.f;
  #pragma unroll
  for (int p = 0; p < 8; p++){
    int j4 = p*64 + lane;
    float4 a = Mr[j4], b = v4[j4];
    s += a.x*b.x + a.y*b.y + a.z*b.z + a.w*b.w;
  }
  #pragma unroll
  for (int o = 32; o > 0; o >>= 1) s += __shfl_down(s, o);
  __shared__ float part[4];
  if (lane == 0){ w[row] = s; part[wave] = s * v[row]; }
  __syncthreads();
  if (threadIdx.x == 0) atomicAdd(&alphaArr[step], part[0]+part[1]+part[2]+part[3]);
}

__global__ __launch_bounds__(256) void k_mv3b(const float* __restrict__ w, const float* __restrict__ vcur,
                                              const float* __restrict__ vprev, float* __restrict__ vnext,
                                              const float* __restrict__ alphaArr, float* __restrict__ betaArr, int step){
  __shared__ float red[256];
  int t = threadIdx.x;
  float alpha = alphaArr[step], bprev = betaArr[step-1];
  float wp[8]; float nrm = 0.f;
  #pragma unroll
  for (int p = 0; p < 8; p++){
    int j = p*256 + t;
    float w2 = w[j] - alpha*vcur[j] - bprev*vprev[j];
    wp[p] = w2; nrm += w2*w2;
  }
  red[t] = nrm; __syncthreads();
  for (int o = 128; o > 0; o >>= 1){ if (t < o) red[t] += red[t+o]; __syncthreads(); }
  float beta = sqrtf(red[0]);
  float invb = 1.0f / fmaxf(beta, 1e-30f);
  #pragma unroll
  for (int p = 0; p < 8; p++){ int j = p*256 + t; vnext[j] = wp[p]*invb; }
  if (t == 0) betaArr[step] = beta;
}

// lambda_max of tridiagonal via lane-parallel Sturm bisection (fp64)
__global__ void k_sturm(const float* __restrict__ alphaArr, const float* __restrict__ betaArr,
                        const float* __restrict__ alphaIn, float* __restrict__ Lbuf){
  __shared__ double sa[LM+1], sb[LM+1];
  int lane = threadIdx.x;
  for (int i = lane; i <= LM; i += 64){ if (i >= 1){ sa[i] = alphaArr[i]; sb[i] = betaArr[i]; } }
  __syncthreads();
  double phi = -1e300, plo = 1e300;
  for (int i = 1 + lane; i <= LM; i += 64){
    double r = (i > 1 ? sb[i-1] : 0.0) + (i < LM ? sb[i] : 0.0);
    phi = fmax(phi, sa[i] + r);
    plo = fmin(plo, sa[i] - r);
  }
  for (int o = 32; o > 0; o >>= 1){
    phi = fmax(phi, __shfl_down(phi, o));
    plo = fmin(plo, __shfl_down(plo, o));
  }
  double hi = __shfl(phi, 0), lo = __shfl(plo, 0);
  for (int round = 0; round < 6; round++){
    double x = lo + (hi - lo) * (double)(lane + 1) / 65.0;
    int cnt = 0;
    double dd = sa[1] - x;
    if (dd < 0) cnt++;
    for (int i = 2; i <= LM; i++){
      double off = sb[i-1];
      if (fabs(dd) < 1e-300) dd = -1e-300;
      dd = sa[i] - x - off*off/dd;
      if (dd < 0) cnt++;
    }
    unsigned long long bal = __ballot(cnt == LM);
    int p = (bal == 0ull) ? 64 : (__ffsll((unsigned long long)bal) - 1);
    double newhi = (p <= 63) ? lo + (hi - lo) * (double)(p + 1) / 65.0 : hi;
    double newlo = (p >= 1)  ? lo + (hi - lo) * (double)p / 65.0       : lo;
    hi = newhi; lo = newlo;
  }
  if (lane == 0){
    double L = 0.5*(lo + hi);
    Lbuf[0] = (float)(1.0 / L);
    Lbuf[1] = (float)(0.5 * (double)alphaIn[0] / L);
  }
}

// ---------------- FISTA ----------------

// iteration 0 elementwise (y0=0): sres = src*Y, delta-half update
__global__ __launch_bounds__(256) void k_A0(const float* __restrict__ Y, const float* __restrict__ src,
                                            float* __restrict__ yd, ushort_t* __restrict__ sresh,
                                            ushort_t* __restrict__ sresl, float* __restrict__ out,
                                            const float* __restrict__ Lbuf){
  int idx = blockIdx.x*256 + threadIdx.x;
  float invL = Lbuf[0], th = Lbuf[1];
  float y = Y[idx], s = src[idx];
  split2(s*y, &sresh[idx], &sresl[idx]);
  float xn = softt(y*invL, th);
  int b = idx >> 11, i = idx & 2047;
  out[(size_t)b*4096 + 2048 + i] = xn;
  yd[idx] = xn;   // c0 = 0 -> y1 = x1
}

// GEMM1: acc[b][i] = sum_k ym[b][k]*W[i][k]; fused res/sres/delta update
__global__ __launch_bounds__(256) void k_gemmA(
    const ushort_t* __restrict__ Wah, const ushort_t* __restrict__ Wal,
    const ushort_t* __restrict__ ymh, const ushort_t* __restrict__ yml,
    const float* __restrict__ Y, const float* __restrict__ src,
    float* __restrict__ yd, float* __restrict__ out,
    ushort_t* __restrict__ sresh, ushort_t* __restrict__ sresl,
    const float* __restrict__ Lbuf, float ck)
{
  f32x4 acc[2][2] = {};
  const int m0 = blockIdx.y * 64, n0 = blockIdx.x * 64;
  gemm_core(ymh, yml, Wah, Wal, m0, n0, SDIM, acc);
  const float invL = Lbuf[0], th = Lbuf[1];
  const int tid = threadIdx.x, lane = tid & 63, wv = tid >> 6;
  const int wm = (wv >> 1) * 32, wn = (wv & 1) * 32;
  const int mm = lane & 15, quad = lane >> 4;
  #pragma unroll
  for (int tm = 0; tm < 2; tm++)
    #pragma unroll
    for (int tn = 0; tn < 2; tn++)
      #pragma unroll
      for (int i = 0; i < 4; i++){
        int brow = m0 + wm + tm*16 + quad*4 + i;
        int col  = n0 + wn + tn*16 + mm;
        int g = brow*SDIM + col;
        float a = acc[tm][tn][i];
        float s = src[g], ydv = yd[g];
        float res = Y[g] - s*a - ydv;
        split2(s*res, &sresh[g], &sresl[g]);
        float xn = softt(ydv + res*invL, th);
        int go = brow*4096 + 2048 + col;
        float xo = out[go];
        out[go] = xn;
        yd[g] = xn + ck*(xn - xo);
      }
}

// GEMM2: acc[b][j] = sum_i sres[b][i]*W[i][j]; fused theta update
template<bool FIRST>
__global__ __launch_bounds__(256) void k_gemmB(
    const ushort_t* __restrict__ Wbh, const ushort_t* __restrict__ Wbl,
    const ushort_t* __restrict__ sresh, const ushort_t* __restrict__ sresl,
    ushort_t* __restrict__ ymh, ushort_t* __restrict__ yml,
    float* __restrict__ out, const float* __restrict__ Lbuf, float ck)
{
  f32x4 acc[2][2] = {};
  const int m0 = blockIdx.y * 64, n0 = blockIdx.x * 64;
  gemm_core(sresh, sresl, Wbh, Wbl, m0, n0, SDIM, acc);
  const float invL = Lbuf[0], th = Lbuf[1];
  const int tid = threadIdx.x, lane = tid & 63, wv = tid >> 6;
  const int wm = (wv >> 1) * 32, wn = (wv & 1) * 32;
  const int mm = lane & 15, quad = lane >> 4;
  #pragma unroll
  for (int tm = 0; tm < 2; tm++)
    #pragma unroll
    for (int tn = 0; tn < 2; tn++)
      #pragma unroll
      for (int i = 0; i < 4; i++){
        int brow = m0 + wm + tm*16 + quad*4 + i;
        int col  = n0 + wn + tn*16 + mm;
        int g = brow*SDIM + col;
        float a = acc[tm][tn][i];
        float ymv = FIRST ? 0.f : (bf2f(ymh[g]) + bf2f(yml[g]));
        float xn = softt(ymv + a*invL, th);
        int go = brow*4096 + col;
        float xo = FIRST ? 0.f : out[go];
        out[go] = xn;
        split2(xn + ck*(xn - xo), &ymh[g], &yml[g]);
      }
}

// ---------------- host ----------------

extern "C" void kernel_launch(void* const* d_in, const int* in_sizes, int n_in,
                              void* d_out, int out_size, void* d_ws, size_t ws_size,
                              hipStream_t stream) {
  const float* src   = (const float*)d_in[0];
  const float* Y     = (const float*)d_in[1];
  const float* W     = (const float*)d_in[2];
  const float* alpha = (const float*)d_in[3];
  float* out = (float*)d_out;
  float* ws  = (float*)d_ws;

  const size_t M1 = 1024*1024;
  float* Mmat = ws;                      // 4M floats (16MB)
  float* yd   = ws + 4*M1;               // 2M floats
  float* lanc = ws + 6*M1;
  float* vb       = lanc;                // 3*2048
  float* wvec     = lanc + 8192;         // 2048
  float* alphaArr = lanc + 16384;        // 128
  float* betaArr  = alphaArr + 128;      // 128
  float* Lbuf     = betaArr + 128;       // 2
  ushort_t* u16 = (ushort_t*)(ws + 7*M1);
  ushort_t* Wah = u16;                   // 4M u16 each
  ushort_t* Wal = u16 + 4*M1;
  ushort_t* Wbh = u16 + 8*M1;
  ushort_t* Wbl = u16 + 12*M1;
  ushort_t* ymh = u16 + 16*M1;           // 2M u16 each
  ushort_t* yml = u16 + 18*M1;
  ushort_t* sresh = u16 + 20*M1;
  ushort_t* sresl = u16 + 22*M1;

  // ---- split W (and W^T) into bf16 hi/lo ----
  k_split<<<dim3(64,64), 256, 0, stream>>>(W, Wah, Wal, Wbh, Wbl);
  // ---- M = W W^T for Lanczos ----
  k_gemmM<<<dim3(32,32), 256, 0, stream>>>(Wah, Wal, Mmat);

  // ---- Lanczos for L = lambda_max ----
  float* v[3] = { vb, vb + SDIM, vb + 2*SDIM };
  k_init<<<1, 256, 0, stream>>>(v[0], v[2], alphaArr, betaArr);
  int cur = 0, prev = 2, nxt = 1;
  for (int step = 1; step <= LM; step++){
    k_Mv<<<512, 256, 0, stream>>>(Mmat, v[cur], wvec, alphaArr, step);
    k_mv3b<<<1, 256, 0, stream>>>(wvec, v[cur], v[prev], v[nxt], alphaArr, betaArr, step);
    prev = cur; cur = nxt; nxt = 3 - cur - prev;
  }
  k_sturm<<<1, 64, 0, stream>>>(alphaArr, betaArr, alpha, Lbuf);

  // ---- momentum coefficients (data independent) ----
  double t = 1.0;
  float ckv[NITER];
  for (int k = 0; k < NITER; k++){
    double tn = 0.5*(1.0 + sqrt(1.0 + 4.0*t*t));
    ckv[k] = (float)((t - 1.0)/tn);
    t = tn;
  }

  // ---- FISTA ----
  k_A0<<<(BATCH*SDIM)/256, 256, 0, stream>>>(Y, src, yd, sresh, sresl, out, Lbuf);
  k_gemmB<true><<<dim3(32,16), 256, 0, stream>>>(Wbh, Wbl, sresh, sresl, ymh, yml, out, Lbuf, ckv[0]);
  for (int k = 1; k < NITER; k++){
    k_gemmA<<<dim3(32,16), 256, 0, stream>>>(Wah, Wal, ymh, yml, Y, src, yd, out, sresh, sresl, Lbuf, ckv[k]);
    k_gemmB<false><<<dim3(32,16), 256, 0, stream>>>(Wbh, Wbl, sresh, sresl, ymh, yml, out, Lbuf, ckv[k]);
  }
  (void)in_sizes; (void)n_in; (void)out_size; (void)ws_size;
}

// Round 3
// 2279.233 us; speedup vs baseline: 3.2914x; 1.2319x over previous
//
#include <hip/hip_runtime.h>
#include <math.h>

#define SDIM 2048
#define BATCH 1024
#define NITER 16
#define LM 96   // Lanczos steps

typedef unsigned short ushort_t;
typedef __attribute__((ext_vector_type(8))) short bf16x8;
typedef __attribute__((ext_vector_type(4))) float f32x4;

#define MFMA(a,b,c) __builtin_amdgcn_mfma_f32_16x16x32_bf16((a),(b),(c),0,0,0)

__device__ __forceinline__ float softt(float v, float th){
  return copysignf(fmaxf(fabsf(v) - th, 0.0f), v);
}

__device__ __forceinline__ float bf2f(ushort_t h){
  return __uint_as_float(((unsigned)h) << 16);
}

// RTNE float -> bf16 hi + bf16 lo split
__device__ __forceinline__ void split2(float x, ushort_t* h, ushort_t* l){
  unsigned u = __float_as_uint(x);
  unsigned hh = (u + 0x7FFFu + ((u >> 16) & 1u)) >> 16;
  float hf = __uint_as_float(hh << 16);
  float r = x - hf;                       // exact
  unsigned v = __float_as_uint(r);
  unsigned ll = (v + 0x7FFFu + ((v >> 16) & 1u)) >> 16;
  *h = (ushort_t)hh; *l = (ushort_t)ll;
}

// async 16B global -> LDS
__device__ __forceinline__ void cp16(const ushort_t* g, ushort_t* l){
  __builtin_amdgcn_global_load_lds(
      (const __attribute__((address_space(1))) unsigned int*)g,
      (__attribute__((address_space(3))) unsigned int*)l, 16, 0, 0);
}

// ---------------- shared MFMA GEMM core (BK=64) ----------------
// C[m][n] = sum_k A[m][k]*B[n][k], A,B row-major bf16 hi/lo split.
// 64x64 tile, BK=64, 256 threads = 4 waves of 32x32 output each.
// LDS layout per buffer: element (row r, k-chunk kp of 8) at ushort offset
// r*64 + (kp ^ (r&7))*8  — matches cp16's forced lane-linear placement AND
// gives 2-way (free) bank aliasing on ds_read_b128.
__device__ __forceinline__ void gemm_core(const ushort_t* __restrict__ Ah, const ushort_t* __restrict__ Al,
                                          const ushort_t* __restrict__ Bh, const ushort_t* __restrict__ Bl,
                                          int m0, int n0, int K, f32x4 acc[2][2])
{
  __shared__ ushort_t lAh[64*64], lAl[64*64], lBh[64*64], lBl[64*64];
  const int tid = threadIdx.x;
  // staging: thread handles chunks tid and tid+256 (rows rr and rr+32, same kp)
  const int rr = tid >> 3;
  const int kp = (tid & 7) ^ (rr & 7);
  const size_t strA = (size_t)32 * K;
  const ushort_t* gAh = Ah + (size_t)(m0 + rr) * K + kp * 8;
  const ushort_t* gAl = Al + (size_t)(m0 + rr) * K + kp * 8;
  const ushort_t* gBh = Bh + (size_t)(n0 + rr) * K + kp * 8;
  const ushort_t* gBl = Bl + (size_t)(n0 + rr) * K + kp * 8;
  ushort_t* dA0 = &lAh[tid * 8];      ushort_t* dA1 = &lAh[(tid + 256) * 8];
  ushort_t* dAl0 = &lAl[tid * 8];     ushort_t* dAl1 = &lAl[(tid + 256) * 8];
  ushort_t* dB0 = &lBh[tid * 8];      ushort_t* dB1 = &lBh[(tid + 256) * 8];
  ushort_t* dBl0 = &lBl[tid * 8];     ushort_t* dBl1 = &lBl[(tid + 256) * 8];

  const int lane = tid & 63, wv = tid >> 6;
  const int wm = (wv >> 1) * 32, wn = (wv & 1) * 32;
  const int mm = lane & 15, quad = lane >> 4;
  const int ra0 = wm + mm, ra1 = wm + 16 + mm;
  const int rb0 = wn + mm, rb1 = wn + 16 + mm;

  const int nk = K / 64;
  for (int kt = 0; kt < nk; kt++){
    cp16(gAh, dA0); cp16(gAh + strA, dA1);
    cp16(gAl, dAl0); cp16(gAl + strA, dAl1);
    cp16(gBh, dB0); cp16(gBh + strA, dB1);
    cp16(gBl, dBl0); cp16(gBl + strA, dBl1);
    gAh += 64; gAl += 64; gBh += 64; gBl += 64;
    __syncthreads();   // drains vmcnt -> staged tile visible
    #pragma unroll
    for (int u = 0; u < 2; u++){
      const int oa0 = ra0*64 + (((u*4 + quad) ^ (ra0 & 7)) << 3);
      const int oa1 = ra1*64 + (((u*4 + quad) ^ (ra1 & 7)) << 3);
      const int ob0 = rb0*64 + (((u*4 + quad) ^ (rb0 & 7)) << 3);
      const int ob1 = rb1*64 + (((u*4 + quad) ^ (rb1 & 7)) << 3);
      bf16x8 ah0 = *(const bf16x8*)&lAh[oa0];
      bf16x8 ah1 = *(const bf16x8*)&lAh[oa1];
      bf16x8 al0 = *(const bf16x8*)&lAl[oa0];
      bf16x8 al1 = *(const bf16x8*)&lAl[oa1];
      bf16x8 bh0 = *(const bf16x8*)&lBh[ob0];
      bf16x8 bh1 = *(const bf16x8*)&lBh[ob1];
      bf16x8 bl0 = *(const bf16x8*)&lBl[ob0];
      bf16x8 bl1 = *(const bf16x8*)&lBl[ob1];
      acc[0][0] = MFMA(ah0, bh0, acc[0][0]);
      acc[0][0] = MFMA(ah0, bl0, acc[0][0]);
      acc[0][0] = MFMA(al0, bh0, acc[0][0]);
      acc[0][1] = MFMA(ah0, bh1, acc[0][1]);
      acc[0][1] = MFMA(ah0, bl1, acc[0][1]);
      acc[0][1] = MFMA(al0, bh1, acc[0][1]);
      acc[1][0] = MFMA(ah1, bh0, acc[1][0]);
      acc[1][0] = MFMA(ah1, bl0, acc[1][0]);
      acc[1][0] = MFMA(al1, bh0, acc[1][0]);
      acc[1][1] = MFMA(ah1, bh1, acc[1][1]);
      acc[1][1] = MFMA(ah1, bl1, acc[1][1]);
      acc[1][1] = MFMA(al1, bh1, acc[1][1]);
    }
    __syncthreads();   // protect LDS before next stage
  }
}

// ---------------- W split / transpose-split ----------------
__global__ __launch_bounds__(256) void k_split(const float* __restrict__ W,
                                               ushort_t* __restrict__ Wah, ushort_t* __restrict__ Wal,
                                               ushort_t* __restrict__ Wbh, ushort_t* __restrict__ Wbl){
  __shared__ float t[32][33];
  const int i0 = blockIdx.y * 32, j0 = blockIdx.x * 32;
  const int r = threadIdx.x >> 3, c = (threadIdx.x & 7) * 4;
  const float4 v = *(const float4*)&W[(size_t)(i0 + r) * SDIM + j0 + c];
  float vv[4] = {v.x, v.y, v.z, v.w};
  ushort_t h[4], l[4];
  #pragma unroll
  for (int q = 0; q < 4; q++){ split2(vv[q], &h[q], &l[q]); t[r][c+q] = vv[q]; }
  *(ushort4*)&Wah[(size_t)(i0 + r) * SDIM + j0 + c] = make_ushort4(h[0],h[1],h[2],h[3]);
  *(ushort4*)&Wal[(size_t)(i0 + r) * SDIM + j0 + c] = make_ushort4(l[0],l[1],l[2],l[3]);
  __syncthreads();
  #pragma unroll
  for (int q = 0; q < 4; q++) split2(t[c+q][r], &h[q], &l[q]);
  *(ushort4*)&Wbh[(size_t)(j0 + r) * SDIM + i0 + c] = make_ushort4(h[0],h[1],h[2],h[3]);
  *(ushort4*)&Wbl[(size_t)(j0 + r) * SDIM + i0 + c] = make_ushort4(l[0],l[1],l[2],l[3]);
}

// M = W * W^T (same nonzero spectrum as W^T W)
__global__ __launch_bounds__(256) void k_gemmM(const ushort_t* __restrict__ Wah, const ushort_t* __restrict__ Wal,
                                               float* __restrict__ Mmat){
  f32x4 acc[2][2] = {};
  const int m0 = blockIdx.y * 64, n0 = blockIdx.x * 64;
  gemm_core(Wah, Wal, Wah, Wal, m0, n0, SDIM, acc);
  const int tid = threadIdx.x, lane = tid & 63, wv = tid >> 6;
  const int wm = (wv >> 1) * 32, wn = (wv & 1) * 32;
  const int mm = lane & 15, quad = lane >> 4;
  #pragma unroll
  for (int tm = 0; tm < 2; tm++)
    #pragma unroll
    for (int tn = 0; tn < 2; tn++)
      #pragma unroll
      for (int i = 0; i < 4; i++){
        int row = m0 + wm + tm*16 + quad*4 + i;
        int col = n0 + wn + tn*16 + mm;
        Mmat[(size_t)row * SDIM + col] = acc[tm][tn][i];
      }
}

// ---------------- Lanczos on M: one kernel per step ----------------
__global__ __launch_bounds__(256) void k_init(float* __restrict__ vRing,
                                              double* __restrict__ dotWV, double* __restrict__ dotWW,
                                              float* __restrict__ betaSq){
  __shared__ float red[256];
  int t = threadIdx.x;
  float vals[8];
  float s = 0.f;
  #pragma unroll
  for (int p = 0; p < 8; p++){
    int j = p*256 + t;
    unsigned h = (unsigned)j * 2654435761u;
    h ^= h >> 16; h *= 2246822519u; h ^= h >> 13;
    float r = (float)(h & 0xFFFFFFu) / 16777216.0f - 0.5f;
    vals[p] = r; s += r*r;
  }
  red[t] = s; __syncthreads();
  for (int o = 128; o > 0; o >>= 1){ if (t < o) red[t] += red[t+o]; __syncthreads(); }
  float inv = rsqrtf(red[0]);
  #pragma unroll
  for (int p = 0; p < 8; p++){
    int j = p*256 + t;
    vRing[SDIM + j] = vals[p]*inv;   // slot 1 = v_1
    vRing[j] = 0.f;                  // slot 0
    vRing[2*SDIM + j] = 0.f;         // slot 2
  }
  if (t < LM+2){ dotWV[t] = 0.0; dotWW[t] = 0.0; betaSq[t] = 0.f; }
}

// step s: reconstruct v_s from w_{s-1} (redundant per block), then 8 rows of M v_s.
// beta^2_{s-1} = ||w||^2 - alpha^2 - beta^2_{s-2}  (fp64 scalar chain)
__global__ __launch_bounds__(256) void k_lstep(const float* __restrict__ M,
    const float* __restrict__ wOld, float* __restrict__ wNew,
    float* __restrict__ vRing, double* __restrict__ dotWV, double* __restrict__ dotWW,
    float* __restrict__ betaSq, int s){
  __shared__ float vs[SDIM];
  __shared__ double pAl[4], pWw[4];
  const int tid = threadIdx.x, bid = blockIdx.x;
  if (s == 1){
    const float* v1 = vRing + SDIM;
    for (int j = tid; j < SDIM; j += 256) vs[j] = v1[j];
  } else {
    const double a  = dotWV[s-1];
    const double ww = dotWW[s-1];
    const float bpSq = betaSq[s-2];
    float bsq = (float)(ww - a*a - (double)bpSq);
    bsq = fmaxf(bsq, 1e-20f);
    const float beta = sqrtf(bsq), invb = 1.0f/beta;
    const float alpha = (float)a, bprev = sqrtf(bpSq);
    const float* vm1 = vRing + ((s-1)%3)*SDIM;
    const float* vm2 = vRing + ((s-2)%3)*SDIM;
    float* vdst = vRing + (s%3)*SDIM;
    for (int j = tid; j < SDIM; j += 256){
      float val = (wOld[j] - alpha*vm1[j] - bprev*vm2[j]) * invb;
      vs[j] = val;
      if (bid == 0) vdst[j] = val;
    }
    if (bid == 0 && tid == 0) betaSq[s-1] = bsq;
  }
  __syncthreads();
  const int wv = tid >> 6, lane = tid & 63;
  double aw = 0.0, ww2 = 0.0;
  #pragma unroll
  for (int rl = 0; rl < 2; rl++){
    const int row = bid*8 + wv*2 + rl;
    const float4* Mr = (const float4*)(M + (size_t)row * SDIM);
    const float4* v4 = (const float4*)vs;
    float acc = 0.f;
    #pragma unroll
    for (int p = 0; p < 8; p++){
      int j4 = p*64 + lane;
      float4 m = Mr[j4], v = v4[j4];
      acc += m.x*v.x + m.y*v.y + m.z*v.z + m.w*v.w;
    }
    #pragma unroll
    for (int o = 32; o > 0; o >>= 1) acc += __shfl_down(acc, o);
    if (lane == 0){
      wNew[row] = acc;
      aw  += (double)acc * (double)vs[row];
      ww2 += (double)acc * (double)acc;
    }
  }
  if (lane == 0){ pAl[wv] = aw; pWw[wv] = ww2; }
  __syncthreads();
  if (tid == 0){
    atomicAdd(&dotWV[s], pAl[0]+pAl[1]+pAl[2]+pAl[3]);
    atomicAdd(&dotWW[s], pWw[0]+pWw[1]+pWw[2]+pWw[3]);
  }
}

// lambda_max of tridiagonal via lane-parallel Sturm bisection (fp64)
__global__ void k_sturm(const double* __restrict__ dotWV, const float* __restrict__ betaSq,
                        const float* __restrict__ alphaIn, float* __restrict__ Lbuf){
  __shared__ double sa[LM+1], sb[LM+1];
  int lane = threadIdx.x;
  for (int i = lane; i <= LM; i += 64){
    if (i >= 1){
      sa[i] = dotWV[i];
      sb[i] = (i < LM) ? sqrt((double)betaSq[i]) : 0.0;
    }
  }
  __syncthreads();
  double phi = -1e300, plo = 1e300;
  for (int i = 1 + lane; i <= LM; i += 64){
    double r = (i > 1 ? sb[i-1] : 0.0) + (i < LM ? sb[i] : 0.0);
    phi = fmax(phi, sa[i] + r);
    plo = fmin(plo, sa[i] - r);
  }
  for (int o = 32; o > 0; o >>= 1){
    phi = fmax(phi, __shfl_down(phi, o));
    plo = fmin(plo, __shfl_down(plo, o));
  }
  double hi = __shfl(phi, 0), lo = __shfl(plo, 0);
  for (int round = 0; round < 6; round++){
    double x = lo + (hi - lo) * (double)(lane + 1) / 65.0;
    int cnt = 0;
    double dd = sa[1] - x;
    if (dd < 0) cnt++;
    for (int i = 2; i <= LM; i++){
      double off = sb[i-1];
      if (fabs(dd) < 1e-300) dd = -1e-300;
      dd = sa[i] - x - off*off/dd;
      if (dd < 0) cnt++;
    }
    unsigned long long bal = __ballot(cnt == LM);
    int p = (bal == 0ull) ? 64 : (__ffsll((unsigned long long)bal) - 1);
    double newhi = (p <= 63) ? lo + (hi - lo) * (double)(p + 1) / 65.0 : hi;
    double newlo = (p >= 1)  ? lo + (hi - lo) * (double)p / 65.0       : lo;
    hi = newhi; lo = newlo;
  }
  if (lane == 0){
    double L = 0.5*(lo + hi);
    Lbuf[0] = (float)(1.0 / L);
    Lbuf[1] = (float)(0.5 * (double)alphaIn[0] / L);
  }
}

// ---------------- FISTA ----------------

// iteration 0 elementwise (y0=0): sres = src*Y, delta-half update
__global__ __launch_bounds__(256) void k_A0(const float* __restrict__ Y, const float* __restrict__ src,
                                            float* __restrict__ yd, ushort_t* __restrict__ sresh,
                                            ushort_t* __restrict__ sresl, float* __restrict__ out,
                                            const float* __restrict__ Lbuf){
  int idx = blockIdx.x*256 + threadIdx.x;
  float invL = Lbuf[0], th = Lbuf[1];
  float y = Y[idx], s = src[idx];
  split2(s*y, &sresh[idx], &sresl[idx]);
  float xn = softt(y*invL, th);
  int b = idx >> 11, i = idx & 2047;
  out[(size_t)b*4096 + 2048 + i] = xn;
  yd[idx] = xn;   // c0 = 0 -> y1 = x1
}

// GEMM1: acc[b][i] = sum_k ym[b][k]*W[i][k]; fused res/sres/delta update
__global__ __launch_bounds__(256) void k_gemmA(
    const ushort_t* __restrict__ Wah, const ushort_t* __restrict__ Wal,
    const ushort_t* __restrict__ ymh, const ushort_t* __restrict__ yml,
    const float* __restrict__ Y, const float* __restrict__ src,
    float* __restrict__ yd, float* __restrict__ out,
    ushort_t* __restrict__ sresh, ushort_t* __restrict__ sresl,
    const float* __restrict__ Lbuf, float ck)
{
  f32x4 acc[2][2] = {};
  const int m0 = blockIdx.y * 64, n0 = blockIdx.x * 64;
  gemm_core(ymh, yml, Wah, Wal, m0, n0, SDIM, acc);
  const float invL = Lbuf[0], th = Lbuf[1];
  const int tid = threadIdx.x, lane = tid & 63, wv = tid >> 6;
  const int wm = (wv >> 1) * 32, wn = (wv & 1) * 32;
  const int mm = lane & 15, quad = lane >> 4;
  #pragma unroll
  for (int tm = 0; tm < 2; tm++)
    #pragma unroll
    for (int tn = 0; tn < 2; tn++)
      #pragma unroll
      for (int i = 0; i < 4; i++){
        int brow = m0 + wm + tm*16 + quad*4 + i;
        int col  = n0 + wn + tn*16 + mm;
        int g = brow*SDIM + col;
        float a = acc[tm][tn][i];
        float s = src[g], ydv = yd[g];
        float res = Y[g] - s*a - ydv;
        split2(s*res, &sresh[g], &sresl[g]);
        float xn = softt(ydv + res*invL, th);
        int go = brow*4096 + 2048 + col;
        float xo = out[go];
        out[go] = xn;
        yd[g] = xn + ck*(xn - xo);
      }
}

// GEMM2: acc[b][j] = sum_i sres[b][i]*W[i][j]; fused theta update
template<bool FIRST>
__global__ __launch_bounds__(256) void k_gemmB(
    const ushort_t* __restrict__ Wbh, const ushort_t* __restrict__ Wbl,
    const ushort_t* __restrict__ sresh, const ushort_t* __restrict__ sresl,
    ushort_t* __restrict__ ymh, ushort_t* __restrict__ yml,
    float* __restrict__ out, const float* __restrict__ Lbuf, float ck)
{
  f32x4 acc[2][2] = {};
  const int m0 = blockIdx.y * 64, n0 = blockIdx.x * 64;
  gemm_core(sresh, sresl, Wbh, Wbl, m0, n0, SDIM, acc);
  const float invL = Lbuf[0], th = Lbuf[1];
  const int tid = threadIdx.x, lane = tid & 63, wv = tid >> 6;
  const int wm = (wv >> 1) * 32, wn = (wv & 1) * 32;
  const int mm = lane & 15, quad = lane >> 4;
  #pragma unroll
  for (int tm = 0; tm < 2; tm++)
    #pragma unroll
    for (int tn = 0; tn < 2; tn++)
      #pragma unroll
      for (int i = 0; i < 4; i++){
        int brow = m0 + wm + tm*16 + quad*4 + i;
        int col  = n0 + wn + tn*16 + mm;
        int g = brow*SDIM + col;
        float a = acc[tm][tn][i];
        float ymv = FIRST ? 0.f : (bf2f(ymh[g]) + bf2f(yml[g]));
        float xn = softt(ymv + a*invL, th);
        int go = brow*4096 + col;
        float xo = FIRST ? 0.f : out[go];
        out[go] = xn;
        split2(xn + ck*(xn - xo), &ymh[g], &yml[g]);
      }
}

// ---------------- host ----------------

extern "C" void kernel_launch(void* const* d_in, const int* in_sizes, int n_in,
                              void* d_out, int out_size, void* d_ws, size_t ws_size,
                              hipStream_t stream) {
  const float* src   = (const float*)d_in[0];
  const float* Y     = (const float*)d_in[1];
  const float* W     = (const float*)d_in[2];
  const float* alpha = (const float*)d_in[3];
  float* out = (float*)d_out;
  float* ws  = (float*)d_ws;

  const size_t M1 = 1024*1024;
  float* Mmat = ws;                      // 4M floats (16MB)
  float* yd   = ws + 4*M1;               // 2M floats
  float* lanc = ws + 6*M1;
  float* w0      = lanc;                 // 2048
  float* w1      = lanc + SDIM;          // 2048
  float* vRing   = lanc + 2*SDIM;        // 3*2048
  double* dotWV  = (double*)(lanc + 5*SDIM);        // 128 doubles (256 floats)
  double* dotWW  = dotWV + 128;                     // 128 doubles
  float* betaSq  = lanc + 5*SDIM + 512;             // 128 floats
  float* Lbuf    = betaSq + 128;                    // 2
  ushort_t* u16 = (ushort_t*)(ws + 7*M1);
  ushort_t* Wah = u16;                   // 4M u16 each
  ushort_t* Wal = u16 + 4*M1;
  ushort_t* Wbh = u16 + 8*M1;
  ushort_t* Wbl = u16 + 12*M1;
  ushort_t* ymh = u16 + 16*M1;           // 2M u16 each
  ushort_t* yml = u16 + 18*M1;
  ushort_t* sresh = u16 + 20*M1;
  ushort_t* sresl = u16 + 22*M1;

  // ---- split W (and W^T) into bf16 hi/lo ----
  k_split<<<dim3(64,64), 256, 0, stream>>>(W, Wah, Wal, Wbh, Wbl);
  // ---- M = W W^T for Lanczos ----
  k_gemmM<<<dim3(32,32), 256, 0, stream>>>(Wah, Wal, Mmat);

  // ---- Lanczos for L = lambda_max: one kernel per step ----
  float* wb[2] = { w0, w1 };
  k_init<<<1, 256, 0, stream>>>(vRing, dotWV, dotWW, betaSq);
  for (int s = 1; s <= LM; s++){
    k_lstep<<<256, 256, 0, stream>>>(Mmat, wb[(s+1)&1], wb[s&1], vRing, dotWV, dotWW, betaSq, s);
  }
  k_sturm<<<1, 64, 0, stream>>>(dotWV, betaSq, alpha, Lbuf);

  // ---- momentum coefficients (data independent) ----
  double t = 1.0;
  float ckv[NITER];
  for (int k = 0; k < NITER; k++){
    double tn = 0.5*(1.0 + sqrt(1.0 + 4.0*t*t));
    ckv[k] = (float)((t - 1.0)/tn);
    t = tn;
  }

  // ---- FISTA ----
  k_A0<<<(BATCH*SDIM)/256, 256, 0, stream>>>(Y, src, yd, sresh, sresl, out, Lbuf);
  k_gemmB<true><<<dim3(32,16), 256, 0, stream>>>(Wbh, Wbl, sresh, sresl, ymh, yml, out, Lbuf, ckv[0]);
  for (int k = 1; k < NITER; k++){
    k_gemmA<<<dim3(32,16), 256, 0, stream>>>(Wah, Wal, ymh, yml, Y, src, yd, out, sresh, sresl, Lbuf, ckv[k]);
    k_gemmB<false><<<dim3(32,16), 256, 0, stream>>>(Wbh, Wbl, sresh, sresl, ymh, yml, out, Lbuf, ckv[k]);
  }
  (void)in_sizes; (void)n_in; (void)out_size; (void)ws_size;
}